// Round 12
// baseline (78.588 us; speedup 1.0000x reference)
//
#include <hip/hip_runtime.h>
#include <hip/hip_bf16.h>

#define CC   256
#define HH   200
#define WW   200
#define KK   1024
#define OH_  14
#define OW_  14
#define OHW  196         // 14*14
#define HW   (HH * WW)   // 40000
#define NG   8           // channel groups (one per XCD)
#define GCH  32          // channels per group
#define ROWB (GCH * 2)   // 64 bytes per (group,position) row
#define PADP 198         // tile pos-dim pad (bank spread)

typedef float f32x4 __attribute__((ext_vector_type(4)));

static __device__ __forceinline__ float lo_bf(unsigned int u) {
  union { unsigned int i; float f; } x; x.i = u << 16; return x.f;
}
static __device__ __forceinline__ float hi_bf(unsigned int u) {
  union { unsigned int i; float f; } x; x.i = u & 0xFFFF0000u; return x.f;
}
static __device__ __forceinline__ unsigned int pack_bf2(float lo, float hi) {
  __hip_bfloat162 h = __float22bfloat162_rn(make_float2(lo, hi));  // RNE
  return *(unsigned int*)&h;   // lo -> low 16 bits (channel 2cp)
}

// ---- transpose+convert: img [C,H*W] f32 -> ws [NG][HW][GCH] bf16 ----------
// Group-major: each XCD's 32-channel slice is a contiguous 2.56 MB block,
// one position = one 64B line (L2-resident); adjacent x -> adjacent 64B rows.
__global__ __launch_bounds__(256) void transpose_bf16_kernel(
    const float* __restrict__ img, unsigned short* __restrict__ ws) {
  __shared__ float tile[64][66];  // pad 66: f2 writes aligned+free, reads 2-way
  const int hw0 = blockIdx.x * 64;
  const int c0  = blockIdx.y * 64;   // spans groups 2*by and 2*by+1
  // load phase: 64ch x 64hw as float4 (4 instrs/thread)
#pragma unroll
  for (int j = 0; j < 4; ++j) {
    const int idx = j * 256 + threadIdx.x;
    const int c   = idx >> 4;        // 0..63
    const int x   = (idx & 15) * 4;  // 0..60
    const float4 v = *(const float4*)&img[(size_t)(c0 + c) * HW + hw0 + x];
    *(float2*)&tile[c][x]     = make_float2(v.x, v.y);
    *(float2*)&tile[c][x + 2] = make_float2(v.z, v.w);
  }
  __syncthreads();
  // write phase: l over [2 groups][64 rows][8 ch-quads]; wave = 512B contig
#pragma unroll
  for (int j = 0; j < 4; ++j) {
    const int l   = j * 256 + threadIdx.x;
    const int gg  = l >> 9;          // 0..1 group-local
    const int rem = l & 511;
    const int r   = rem >> 3;        // 0..63 hw row
    const int q   = rem & 7;         // ch quad
    const int cl  = gg * 32 + 4 * q; // tile row base
    const float a = tile[cl + 0][r];
    const float b = tile[cl + 1][r];
    const float c = tile[cl + 2][r];
    const float d = tile[cl + 3][r];
    const __hip_bfloat16 ba = __float2bfloat16(a);  // RNE
    const __hip_bfloat16 bb = __float2bfloat16(b);
    const __hip_bfloat16 bc = __float2bfloat16(c);
    const __hip_bfloat16 bd = __float2bfloat16(d);
    const unsigned int lo = (unsigned int)*(const unsigned short*)&ba |
                            ((unsigned int)*(const unsigned short*)&bb << 16);
    const unsigned int hi = (unsigned int)*(const unsigned short*)&bc |
                            ((unsigned int)*(const unsigned short*)&bd << 16);
    const int G = (c0 >> 5) + gg;    // absolute group
    *(uint2*)&ws[(size_t)G * HW * GCH + (size_t)(hw0 + r) * GCH + 4 * q] =
        make_uint2(lo, hi);
  }
}

// ---------- per-box sample table (row-byte-offset indices, folded wts) ----
__device__ __forceinline__ void precompute_pos(
    const float* __restrict__ boxes, int k, int tid,
    int4* sidx, float4* sw, int idx_scale) {
  if (tid < OHW) {
    const float xmin = boxes[k * 4 + 0];
    const float ymin = boxes[k * 4 + 1];
    const float xmax = boxes[k * 4 + 2];
    const float ymax = boxes[k * 4 + 3];
    const float a11 = (xmax - xmin) / 14.0f;
    const float a22 = (ymax - ymin) / 14.0f;
    const int ow = tid % OW_;
    const int oh = tid / OW_;
    // replicate reference FP sequence exactly
    const float xi = a11 * (float)ow + xmin;
    const float yi = a22 * (float)oh + ymin;
    const float gx = (xi - 100.0f) / 200.0f * 2.0f;
    const float gy = (yi - 100.0f) / 200.0f * 2.0f;
    const float x  = ((gx + 1.0f) * 200.0f - 1.0f) * 0.5f;
    const float y  = ((gy + 1.0f) * 200.0f - 1.0f) * 0.5f;
    const float fx0 = floorf(x);
    const float fy0 = floorf(y);
    const float wx = x - fx0;
    const float wy = y - fy0;
    const int x0 = (int)fx0, y0 = (int)fy0;
    const int x1 = x0 + 1,   y1 = y0 + 1;
    const bool vx0 = (x0 >= 0) & (x0 < WW);
    const bool vx1 = (x1 >= 0) & (x1 < WW);
    const bool vy0 = (y0 >= 0) & (y0 < HH);
    const bool vy1 = (y1 >= 0) & (y1 < HH);
    const int cx0 = min(max(x0, 0), WW - 1);
    const int cx1 = min(max(x1, 0), WW - 1);
    const int cy0 = min(max(y0, 0), HH - 1);
    const int cy1 = min(max(y1, 0), HH - 1);
    sidx[tid] = make_int4((cy0 * WW + cx0) * idx_scale, (cy0 * WW + cx1) * idx_scale,
                          (cy1 * WW + cx0) * idx_scale, (cy1 * WW + cx1) * idx_scale);
    sw[tid] = make_float4((1.0f - wy) * (1.0f - wx) * (float)(vy0 && vx0),
                          (1.0f - wy) * wx          * (float)(vy0 && vx1),
                          wy          * (1.0f - wx) * (float)(vy1 && vx0),
                          wy          * wx          * (float)(vy1 && vx1));
  }
}

// One position p_: 32 lanes (16cp x 2xs) cover its x-pair = contiguous 128B
// per y-row; thread loads its xs-column's two y-rows; x-sum via shfl_xor(16).
#define GATHER_P(p_)                                                          \
  {                                                                           \
    const int4   id = sidx[p_];                                               \
    const float4 wt = sw[p_];                                                 \
    const int   off0 = xs ? id.y : id.x;                                      \
    const int   off1 = xs ? id.w : id.z;                                      \
    const float w0   = xs ? wt.y : wt.x;                                      \
    const float w1   = xs ? wt.w : wt.z;                                      \
    const unsigned int u0 = *(const unsigned int*)(wsb + off0);               \
    const unsigned int u1 = *(const unsigned int*)(wsb + off1);               \
    float vlo = w0 * lo_bf(u0) + w1 * lo_bf(u1);                              \
    float vhi = w0 * hi_bf(u0) + w1 * hi_bf(u1);                              \
    vlo += __shfl_xor(vlo, 16);                                               \
    vhi += __shfl_xor(vhi, 16);                                               \
    if (xs == 0) tile_u[cp][p_] = pack_bf2(vlo, vhi);                         \
  }

// ---------- gather: ws [NG][HW][GCH] bf16 -> out [K,C,OH,OW] f32 ----------
// blockIdx.x = k*8 + g (g = b&7 = XCD id under round-robin dispatch) ->
// each XCD reads only its own contiguous 2.56 MB slice (L2-resident).
// Lanes (cp, xs, pq): gather requests are 2x128B contiguous per position
// (vs 4x64B scattered) -> half the L2 requests, double the request size.
__global__ __launch_bounds__(256, 8) void crop_resize_bf16(
    const unsigned short* __restrict__ ws, const float* __restrict__ boxes,
    float* __restrict__ out) {
  __shared__ int4         sidx[OHW];
  __shared__ float4       sw[OHW];
  __shared__ unsigned int tile_u[16][PADP];  // 12.4 KB, [ch-pair][position]

  const int b   = blockIdx.x;
  const int g   = b & 7;
  const int k   = b >> 3;
  const int tid = threadIdx.x;
  precompute_pos(boxes, k, tid, sidx, sw, ROWB);  // row byte offsets (row*64)
  __syncthreads();

  const int cp = tid & 15;          // channel pair 0..15
  const int xs = (tid >> 4) & 1;    // x-corner select
  const int pq = tid >> 5;          // position offset 0..7
  const char* wsb = (const char*)ws + ((size_t)g * HW * GCH * 2 + cp * 4);

  // gather phase: positions pq + 8*it (24 full iters) + tail 192..195
#pragma unroll 4
  for (int it = 0; it < 24; ++it) {
    GATHER_P(pq + 8 * it);
  }
  if (pq < 4) GATHER_P(192 + pq);
  __syncthreads();

  // store phase: flat f4 over [32 ch][49 f4] = 25088 B contiguous out block
  char* ob = (char*)out + (((size_t)k * CC + g * GCH) * OHW) * 4;
#pragma unroll
  for (int t = 0; t < 6; ++t) {
    const int j  = t * 256 + tid;   // 0..1535
    const int cc = j / 49;          // channel 0..31 (magic-mul)
    const int q  = j - cc * 49;
    const uint2 a = *(const uint2*)&tile_u[cc >> 1][4 * q];
    const uint2 c = *(const uint2*)&tile_u[cc >> 1][4 * q + 2];
    const f32x4 v = (cc & 1)
        ? (f32x4){hi_bf(a.x), hi_bf(a.y), hi_bf(c.x), hi_bf(c.y)}
        : (f32x4){lo_bf(a.x), lo_bf(a.y), lo_bf(c.x), lo_bf(c.y)};
    *(f32x4*)(ob + (size_t)j * 16) = v;
  }
  if (tid < 32) {                   // tail: j = 1536..1567
    const int j  = 1536 + tid;
    const int cc = j / 49;
    const int q  = j - cc * 49;
    const uint2 a = *(const uint2*)&tile_u[cc >> 1][4 * q];
    const uint2 c = *(const uint2*)&tile_u[cc >> 1][4 * q + 2];
    const f32x4 v = (cc & 1)
        ? (f32x4){hi_bf(a.x), hi_bf(a.y), hi_bf(c.x), hi_bf(c.y)}
        : (f32x4){lo_bf(a.x), lo_bf(a.y), lo_bf(c.x), lo_bf(c.y)};
    *(f32x4*)(ob + (size_t)j * 16) = v;
  }
}

// ---------- fallback direct kernel (ws too small) ----------
#define NCHUNK 32
#define CPB    (CC / NCHUNK)  // 8
__global__ __launch_bounds__(256) void crop_resize_direct(
    const float* __restrict__ img, const float* __restrict__ boxes,
    float* __restrict__ out) {
  __shared__ int4   sidx[OHW];
  __shared__ float4 sw[OHW];
  const int k      = blockIdx.x;
  const int cchunk = blockIdx.y;
  const int tid    = threadIdx.x;
  precompute_pos(boxes, k, tid, sidx, sw, 1);
  __syncthreads();

  const int c0 = cchunk * CPB;
  const int total = CPB * OHW;
  float* outk = out + (size_t)k * CC * OHW + (size_t)c0 * OHW;
  const float* imgc0 = img + (size_t)c0 * HW;

#pragma unroll 4
  for (int i = tid; i < total; i += 256) {
    const int c   = i / OHW;
    const int pos = i - c * OHW;
    const int4   id = sidx[pos];
    const float4 wd = sw[pos];
    const float* p  = imgc0 + c * HW;
    const float v = wd.x * p[id.x] + wd.y * p[id.y] +
                    wd.z * p[id.z] + wd.w * p[id.w];
    outk[i] = v;
  }
}

extern "C" void kernel_launch(void* const* d_in, const int* in_sizes, int n_in,
                              void* d_out, int out_size, void* d_ws, size_t ws_size,
                              hipStream_t stream) {
  const float* img   = (const float*)d_in[0];
  const float* boxes = (const float*)d_in[1];
  float* out = (float*)d_out;
  const size_t need = (size_t)HW * CC * sizeof(unsigned short);  // 20.48 MB
  if (ws_size >= need) {
    unsigned short* wsimg = (unsigned short*)d_ws;
    hipLaunchKernelGGL(transpose_bf16_kernel, dim3(HW / 64, CC / 64), dim3(256),
                       0, stream, img, wsimg);
    hipLaunchKernelGGL(crop_resize_bf16, dim3(KK * NG), dim3(256), 0, stream,
                       wsimg, boxes, out);
  } else {
    hipLaunchKernelGGL(crop_resize_direct, dim3(KK, NCHUNK), dim3(256), 0,
                       stream, img, boxes, out);
  }
}

// Round 13
// 55.552 us; speedup vs baseline: 1.4147x; 1.4147x over previous
//
#include <hip/hip_runtime.h>
#include <hip/hip_bf16.h>

#define CC   256
#define HH   200
#define WW   200
#define KK   1024
#define OH_  14
#define OW_  14
#define OHW  196         // 14*14
#define HW   (HH * WW)   // 40000
#define NG   8           // channel groups (one per XCD)
#define GCH  32          // channels per group
#define ROWB (GCH * 2)   // 64 bytes per (group,position) row
#define PADP 198         // tile pos-dim pad (bank spread)

typedef float f32x4 __attribute__((ext_vector_type(4)));

static __device__ __forceinline__ float lo_bf(unsigned int u) {
  union { unsigned int i; float f; } x; x.i = u << 16; return x.f;
}
static __device__ __forceinline__ float hi_bf(unsigned int u) {
  union { unsigned int i; float f; } x; x.i = u & 0xFFFF0000u; return x.f;
}
static __device__ __forceinline__ unsigned int pack_bf2(float lo, float hi) {
  __hip_bfloat162 h = __float22bfloat162_rn(make_float2(lo, hi));  // RNE
  return *(unsigned int*)&h;   // lo -> low 16 bits (channel 2cp)
}

// ---- transpose+convert: img [C,H*W] f32 -> ws [NG][HW][GCH] bf16 ----------
// Group-major: each XCD's 32-channel slice is a contiguous 2.56 MB block,
// one position = one 64B line (L2-resident, zero line waste).
__global__ __launch_bounds__(256) void transpose_bf16_kernel(
    const float* __restrict__ img, unsigned short* __restrict__ ws) {
  __shared__ float tile[64][66];  // pad 66: f2 writes aligned+free, reads 2-way
  const int hw0 = blockIdx.x * 64;
  const int c0  = blockIdx.y * 64;   // spans groups 2*by and 2*by+1
  // load phase: 64ch x 64hw as float4 (4 instrs/thread)
#pragma unroll
  for (int j = 0; j < 4; ++j) {
    const int idx = j * 256 + threadIdx.x;
    const int c   = idx >> 4;        // 0..63
    const int x   = (idx & 15) * 4;  // 0..60
    const float4 v = *(const float4*)&img[(size_t)(c0 + c) * HW + hw0 + x];
    *(float2*)&tile[c][x]     = make_float2(v.x, v.y);
    *(float2*)&tile[c][x + 2] = make_float2(v.z, v.w);
  }
  __syncthreads();
  // write phase: l over [2 groups][64 rows][8 ch-quads]; wave = 512B contig
#pragma unroll
  for (int j = 0; j < 4; ++j) {
    const int l   = j * 256 + threadIdx.x;
    const int gg  = l >> 9;          // 0..1 group-local
    const int rem = l & 511;
    const int r   = rem >> 3;        // 0..63 hw row
    const int q   = rem & 7;         // ch quad
    const int cl  = gg * 32 + 4 * q; // tile row base
    const float a = tile[cl + 0][r];
    const float b = tile[cl + 1][r];
    const float c = tile[cl + 2][r];
    const float d = tile[cl + 3][r];
    const __hip_bfloat16 ba = __float2bfloat16(a);  // RNE
    const __hip_bfloat16 bb = __float2bfloat16(b);
    const __hip_bfloat16 bc = __float2bfloat16(c);
    const __hip_bfloat16 bd = __float2bfloat16(d);
    const unsigned int lo = (unsigned int)*(const unsigned short*)&ba |
                            ((unsigned int)*(const unsigned short*)&bb << 16);
    const unsigned int hi = (unsigned int)*(const unsigned short*)&bc |
                            ((unsigned int)*(const unsigned short*)&bd << 16);
    const int G = (c0 >> 5) + gg;    // absolute group
    *(uint2*)&ws[(size_t)G * HW * GCH + (size_t)(hw0 + r) * GCH + 4 * q] =
        make_uint2(lo, hi);
  }
}

// ---------- per-box sample table (row-byte-offset indices, folded wts) ----
__device__ __forceinline__ void precompute_pos(
    const float* __restrict__ boxes, int k, int tid,
    int4* sidx, float4* sw, int idx_scale) {
  if (tid < OHW) {
    const float xmin = boxes[k * 4 + 0];
    const float ymin = boxes[k * 4 + 1];
    const float xmax = boxes[k * 4 + 2];
    const float ymax = boxes[k * 4 + 3];
    const float a11 = (xmax - xmin) / 14.0f;
    const float a22 = (ymax - ymin) / 14.0f;
    const int ow = tid % OW_;
    const int oh = tid / OW_;
    // replicate reference FP sequence exactly
    const float xi = a11 * (float)ow + xmin;
    const float yi = a22 * (float)oh + ymin;
    const float gx = (xi - 100.0f) / 200.0f * 2.0f;
    const float gy = (yi - 100.0f) / 200.0f * 2.0f;
    const float x  = ((gx + 1.0f) * 200.0f - 1.0f) * 0.5f;
    const float y  = ((gy + 1.0f) * 200.0f - 1.0f) * 0.5f;
    const float fx0 = floorf(x);
    const float fy0 = floorf(y);
    const float wx = x - fx0;
    const float wy = y - fy0;
    const int x0 = (int)fx0, y0 = (int)fy0;
    const int x1 = x0 + 1,   y1 = y0 + 1;
    const bool vx0 = (x0 >= 0) & (x0 < WW);
    const bool vx1 = (x1 >= 0) & (x1 < WW);
    const bool vy0 = (y0 >= 0) & (y0 < HH);
    const bool vy1 = (y1 >= 0) & (y1 < HH);
    const int cx0 = min(max(x0, 0), WW - 1);
    const int cx1 = min(max(x1, 0), WW - 1);
    const int cy0 = min(max(y0, 0), HH - 1);
    const int cy1 = min(max(y1, 0), HH - 1);
    sidx[tid] = make_int4((cy0 * WW + cx0) * idx_scale, (cy0 * WW + cx1) * idx_scale,
                          (cy1 * WW + cx0) * idx_scale, (cy1 * WW + cx1) * idx_scale);
    sw[tid] = make_float4((1.0f - wy) * (1.0f - wx) * (float)(vy0 && vx0),
                          (1.0f - wy) * wx          * (float)(vy0 && vx1),
                          wy          * (1.0f - wx) * (float)(vy1 && vx0),
                          wy          * wx          * (float)(vy1 && vx1));
  }
}

// Gather+blend position p_ (channels 2cp, 2cp+1) into packed tile_u[cp][p].
#define GATHER_ONE(p_)                                                        \
  {                                                                           \
    const int4   id = sidx[p_];                                               \
    const float4 wt = sw[p_];                                                 \
    const unsigned int u0 = *(const unsigned int*)(wsb + id.x);               \
    const unsigned int u1 = *(const unsigned int*)(wsb + id.y);               \
    const unsigned int u2 = *(const unsigned int*)(wsb + id.z);               \
    const unsigned int u3 = *(const unsigned int*)(wsb + id.w);               \
    const float vlo = wt.x * lo_bf(u0) + wt.y * lo_bf(u1) +                   \
                      wt.z * lo_bf(u2) + wt.w * lo_bf(u3);                    \
    const float vhi = wt.x * hi_bf(u0) + wt.y * hi_bf(u1) +                   \
                      wt.z * hi_bf(u2) + wt.w * hi_bf(u3);                    \
    tile_u[cp][p_] = pack_bf2(vlo, vhi);                                      \
  }

// ---------- gather: ws [NG][HW][GCH] bf16 -> out [K,C,OH,OW] f32 ----------
// blockIdx.x = k*8 + g (g = b&7 = XCD id under round-robin dispatch) ->
// each XCD reads only its own contiguous 2.56 MB slice (L2-resident).
// Single chunk, packed-bf16 tile (12.4 KB) -> 8 blocks/CU for phase overlap.
// One barrier; store phase = flat f4 sweep -> perfect 1KB wave stores.
__global__ __launch_bounds__(256, 8) void crop_resize_bf16(
    const unsigned short* __restrict__ ws, const float* __restrict__ boxes,
    float* __restrict__ out) {
  __shared__ int4         sidx[OHW];
  __shared__ float4       sw[OHW];
  __shared__ unsigned int tile_u[16][PADP];  // 12.4 KB, [ch-pair][position]

  const int b   = blockIdx.x;
  const int g   = b & 7;
  const int k   = b >> 3;
  const int tid = threadIdx.x;
  precompute_pos(boxes, k, tid, sidx, sw, ROWB);  // row byte offsets (row*64)
  __syncthreads();

  const int cp = tid & 15;   // channel pair 0..15 (channels 2cp, 2cp+1)
  const int po = tid >> 4;   // position offset 0..15
  const char* wsb = (const char*)ws + ((size_t)g * HW * GCH * 2 + cp * 4);

  // gather phase: positions po + 16*it (12 full iters) + tail 192..195
#pragma unroll 4
  for (int it = 0; it < 12; ++it) {
    GATHER_ONE(po + 16 * it);
  }
  if (po < 4) GATHER_ONE(192 + po);
  __syncthreads();

  // store phase: flat f4 over [32 ch][49 f4] = 25088 B contiguous out block
  char* ob = (char*)out + (((size_t)k * CC + g * GCH) * OHW) * 4;
#pragma unroll
  for (int t = 0; t < 6; ++t) {
    const int j  = t * 256 + tid;   // 0..1535
    const int cc = j / 49;          // channel 0..31 (magic-mul)
    const int q  = j - cc * 49;
    const uint2 a = *(const uint2*)&tile_u[cc >> 1][4 * q];
    const uint2 c = *(const uint2*)&tile_u[cc >> 1][4 * q + 2];
    const f32x4 v = (cc & 1)
        ? (f32x4){hi_bf(a.x), hi_bf(a.y), hi_bf(c.x), hi_bf(c.y)}
        : (f32x4){lo_bf(a.x), lo_bf(a.y), lo_bf(c.x), lo_bf(c.y)};
    *(f32x4*)(ob + (size_t)j * 16) = v;
  }
  if (tid < 32) {                   // tail: j = 1536..1567
    const int j  = 1536 + tid;
    const int cc = j / 49;
    const int q  = j - cc * 49;
    const uint2 a = *(const uint2*)&tile_u[cc >> 1][4 * q];
    const uint2 c = *(const uint2*)&tile_u[cc >> 1][4 * q + 2];
    const f32x4 v = (cc & 1)
        ? (f32x4){hi_bf(a.x), hi_bf(a.y), hi_bf(c.x), hi_bf(c.y)}
        : (f32x4){lo_bf(a.x), lo_bf(a.y), lo_bf(c.x), lo_bf(c.y)};
    *(f32x4*)(ob + (size_t)j * 16) = v;
  }
}

// ---------- fallback direct kernel (ws too small) ----------
#define NCHUNK 32
#define CPB    (CC / NCHUNK)  // 8
__global__ __launch_bounds__(256) void crop_resize_direct(
    const float* __restrict__ img, const float* __restrict__ boxes,
    float* __restrict__ out) {
  __shared__ int4   sidx[OHW];
  __shared__ float4 sw[OHW];
  const int k      = blockIdx.x;
  const int cchunk = blockIdx.y;
  const int tid    = threadIdx.x;
  precompute_pos(boxes, k, tid, sidx, sw, 1);
  __syncthreads();

  const int c0 = cchunk * CPB;
  const int total = CPB * OHW;
  float* outk = out + (size_t)k * CC * OHW + (size_t)c0 * OHW;
  const float* imgc0 = img + (size_t)c0 * HW;

#pragma unroll 4
  for (int i = tid; i < total; i += 256) {
    const int c   = i / OHW;
    const int pos = i - c * OHW;
    const int4   id = sidx[pos];
    const float4 wd = sw[pos];
    const float* p  = imgc0 + c * HW;
    const float v = wd.x * p[id.x] + wd.y * p[id.y] +
                    wd.z * p[id.z] + wd.w * p[id.w];
    outk[i] = v;
  }
}

extern "C" void kernel_launch(void* const* d_in, const int* in_sizes, int n_in,
                              void* d_out, int out_size, void* d_ws, size_t ws_size,
                              hipStream_t stream) {
  const float* img   = (const float*)d_in[0];
  const float* boxes = (const float*)d_in[1];
  float* out = (float*)d_out;
  const size_t need = (size_t)HW * CC * sizeof(unsigned short);  // 20.48 MB
  if (ws_size >= need) {
    unsigned short* wsimg = (unsigned short*)d_ws;
    hipLaunchKernelGGL(transpose_bf16_kernel, dim3(HW / 64, CC / 64), dim3(256),
                       0, stream, img, wsimg);
    hipLaunchKernelGGL(crop_resize_bf16, dim3(KK * NG), dim3(256), 0, stream,
                       wsimg, boxes, out);
  } else {
    hipLaunchKernelGGL(crop_resize_direct, dim3(KK, NCHUNK), dim3(256), 0,
                       stream, img, boxes, out);
  }
}